// Round 3
// baseline (52.753 us; speedup 1.0000x reference)
//
#include <hip/hip_runtime.h>
#include <stdint.h>

#define BB 1024    // batches
#define TT 1024    // input bits per batch
#define NN 2048    // neurons
#define NBITS 16   // address bits
#define MM 65536   // table entries per neuron
#define BW (BB/64) // 16 uint64 words per t (batch-dimension bit-packing)
#define LK 8       // lookups (batches) per thread

// Kernel 1: transpose+pack input_bits (B x T int32) into bitsT[t][w] where
// bit j of bitsT[t][w] = (input_bits[w*64+j][t] != 0).
// grid: (T/64, B/64), block: 256 threads (4 waves, each wave covers 16 t's).
__global__ void pack_transpose_kernel(const int* __restrict__ in,
                                      unsigned long long* __restrict__ bitsT) {
    const int lane = threadIdx.x & 63;
    const int wave = threadIdx.x >> 6;
    const int w  = blockIdx.y;                 // batch word index
    const int t0 = blockIdx.x * 64 + wave * 16;
    const int b  = w * 64 + lane;
    const int* row = in + (size_t)b * TT;
    #pragma unroll
    for (int i = 0; i < 16; ++i) {
        const int t = t0 + i;
        const int v = row[t];                  // each lane streams 64B of its row
        unsigned long long m = __ballot(v != 0);
        if (lane == 0) bitsT[(size_t)t * BW + w] = m;
    }
}

// Kernel 2: for each (b, n): addr = sum_k bit(b, conn[n][k]) << (15-k);
// out[b][n] = (table[n][addr] == 1.0f) as int32 0/1.
// grid: (N/16, B/128), block 256. Thread (tn = tid&15, s = tid>>4) handles
// neuron n = bx*16+tn, batches b0..b0+7 with b0 = by*128 + s*8.
// 16 waves/CU occupancy; 8 independent HBM gathers in flight per thread.
__global__ __launch_bounds__(256) void lookup_kernel(
        const int* __restrict__ conn,
        const float* __restrict__ table,
        const unsigned long long* __restrict__ bitsT,
        int* __restrict__ out) {
    const int tn = threadIdx.x & 15;
    const int s  = threadIdx.x >> 4;
    const int n  = blockIdx.x * 16 + tn;
    const int b0 = blockIdx.y * (16 * LK) + s * LK;

    // conn row: 64B via 4x dwordx4
    const int4* c4 = (const int4*)(conn + (size_t)n * NBITS);
    const int4 c0 = c4[0], c1 = c4[1], c2 = c4[2], c3 = c4[3];
    const int tk[NBITS] = {c0.x, c0.y, c0.z, c0.w, c1.x, c1.y, c1.z, c1.w,
                           c2.x, c2.y, c2.z, c2.w, c3.x, c3.y, c3.z, c3.w};

    // per-bit batch masks for b0..b0+LK-1 (LK bits each), from L2-resident bitsT
    const int w  = b0 >> 6;
    const int jb = b0 & 63;
    unsigned int hw[NBITS];
    #pragma unroll
    for (int k = 0; k < NBITS; ++k) {
        unsigned long long word = bitsT[(size_t)tk[k] * BW + w];
        hw[k] = (unsigned int)(word >> jb) & 0xFFu;
    }

    // addresses (pure VALU)
    unsigned int addr[LK];
    #pragma unroll
    for (int j = 0; j < LK; ++j) {
        unsigned int a = 0;
        #pragma unroll
        for (int k = 0; k < NBITS; ++k)
            a |= ((hw[k] >> j) & 1u) << (NBITS - 1 - k);
        addr[j] = a;
    }

    // all LK random gathers in flight before any dependent use
    const float* trow = table + (size_t)n * MM;
    float v[LK];
    #pragma unroll
    for (int j = 0; j < LK; ++j) v[j] = trow[addr[j]];

    #pragma unroll
    for (int j = 0; j < LK; ++j)
        out[(size_t)(b0 + j) * NN + n] = (v[j] == 1.0f) ? 1 : 0;
}

extern "C" void kernel_launch(void* const* d_in, const int* in_sizes, int n_in,
                              void* d_out, int out_size, void* d_ws, size_t ws_size,
                              hipStream_t stream) {
    const int*   in_bits = (const int*)d_in[0];    // (B, T) int32
    const int*   conn    = (const int*)d_in[1];    // (N, NB) int32
    const float* table   = (const float*)d_in[2];  // (N, M) float32
    int* out = (int*)d_out;                        // (B, N) bool -> int32 0/1

    unsigned long long* bitsT = (unsigned long long*)d_ws; // 128 KB needed

    dim3 g1(TT / 64, BB / 64);
    pack_transpose_kernel<<<g1, 256, 0, stream>>>(in_bits, bitsT);

    dim3 g2(NN / 16, BB / (16 * LK));
    lookup_kernel<<<g2, 256, 0, stream>>>(conn, table, bitsT, out);
}

// Round 4
// 49.961 us; speedup vs baseline: 1.0559x; 1.0559x over previous
//
#include <hip/hip_runtime.h>
#include <stdint.h>

#define BB 1024    // batches
#define TT 1024    // input bits per batch
#define NN 2048    // neurons
#define NBITS 16   // address bits
#define MM 65536   // table entries per neuron
#define BW (BB/64) // 16 uint64 words per t (batch-dimension bit-packing)
#define NPB 16     // neurons per block
#define BPB 256    // batches per block
#define LK 16      // lookups per thread

// Kernel 1: transpose+pack input_bits (B x T int32) into bitsT[t][w] where
// bit j of bitsT[t][w] = (input_bits[w*64+j][t] != 0).
__global__ void pack_transpose_kernel(const int* __restrict__ in,
                                      unsigned long long* __restrict__ bitsT) {
    const int lane = threadIdx.x & 63;
    const int wave = threadIdx.x >> 6;
    const int w  = blockIdx.y;                 // batch word index
    const int t0 = blockIdx.x * 64 + wave * 16;
    const int b  = w * 64 + lane;
    const int* row = in + (size_t)b * TT;
    #pragma unroll
    for (int i = 0; i < 16; ++i) {
        const int t = t0 + i;
        const int v = row[t];
        unsigned long long m = __ballot(v != 0);
        if (lane == 0) bitsT[(size_t)t * BW + w] = m;
    }
}

// Kernel 2: per block: 16 neurons x 256 batches. Stage the 256 needed
// bitsT word-groups (8KB) into LDS once (coalesced), then the inner loop
// touches global memory ONLY for the table gather + output store.
// grid (NN/16, BB/256) = (128, 4); block 256.
__global__ __launch_bounds__(256) void lookup_kernel(
        const int* __restrict__ conn,
        const float* __restrict__ table,
        const unsigned long long* __restrict__ bitsT,
        int* __restrict__ out) {
    // entry (k, nl) occupies 9 dwords (8 data + 1 pad): stride 9 is coprime
    // with 32 banks -> lookup-phase reads spread across banks (<=2-way).
    __shared__ uint32_t sbits[NPB * NBITS * 9];   // 9216 B

    const int tid = threadIdx.x;
    const int n0  = blockIdx.x * NPB;
    const int w0  = blockIdx.y * (BPB / 64);      // first u64 word for this block

    // ---- stage phase: thread tid <-> (nl_s = tid>>4, k_s = tid&15) ----
    {
        const int k_s  = tid & 15;
        const int nl_s = tid >> 4;
        const int t = conn[n0 * NBITS + tid];     // coalesced 1KB
        const ulonglong2* p = (const ulonglong2*)(bitsT + (size_t)t * BW + w0);
        const ulonglong2 a = p[0], b = p[1];      // 32B: words w0..w0+3
        uint32_t* dst = &sbits[(k_s * NPB + nl_s) * 9];
        dst[0] = (uint32_t)a.x; dst[1] = (uint32_t)(a.x >> 32);
        dst[2] = (uint32_t)a.y; dst[3] = (uint32_t)(a.y >> 32);
        dst[4] = (uint32_t)b.x; dst[5] = (uint32_t)(b.x >> 32);
        dst[6] = (uint32_t)b.y; dst[7] = (uint32_t)(b.y >> 32);
    }
    __syncthreads();

    // ---- lookup phase: thread tid <-> (nl = tid&15, s = tid>>4) ----
    // nl = low bits -> 16 consecutive n per 16 lanes -> 64B store segments.
    const int nl = tid & 15;
    const int s  = tid >> 4;
    const int n  = n0 + nl;
    const int b0 = blockIdx.y * BPB + s * LK;

    // batch b0+j is bit ((s&1)*16 + j) of dword (s>>1) of entry (k, nl)
    unsigned int hw[NBITS];
    #pragma unroll
    for (int k = 0; k < NBITS; ++k) {
        const uint32_t wv = sbits[(k * NPB + nl) * 9 + (s >> 1)];
        hw[k] = (wv >> ((s & 1) * 16)) & 0xFFFFu;
    }

    unsigned int addr[LK];
    #pragma unroll
    for (int j = 0; j < LK; ++j) {
        unsigned int a = 0;
        #pragma unroll
        for (int k = 0; k < NBITS; ++k)
            a |= ((hw[k] >> j) & 1u) << (NBITS - 1 - k);
        addr[j] = a;
    }

    // all LK random gathers in flight before any dependent use
    const float* trow = table + (size_t)n * MM;
    float v[LK];
    #pragma unroll
    for (int j = 0; j < LK; ++j) v[j] = trow[addr[j]];

    #pragma unroll
    for (int j = 0; j < LK; ++j) {
        const int r = (v[j] == 1.0f) ? 1 : 0;
        __builtin_nontemporal_store(r, &out[(size_t)(b0 + j) * NN + n]);
    }
}

extern "C" void kernel_launch(void* const* d_in, const int* in_sizes, int n_in,
                              void* d_out, int out_size, void* d_ws, size_t ws_size,
                              hipStream_t stream) {
    const int*   in_bits = (const int*)d_in[0];    // (B, T) int32
    const int*   conn    = (const int*)d_in[1];    // (N, NB) int32
    const float* table   = (const float*)d_in[2];  // (N, M) float32
    int* out = (int*)d_out;                        // (B, N) bool -> int32 0/1

    unsigned long long* bitsT = (unsigned long long*)d_ws; // 128 KB needed

    dim3 g1(TT / 64, BB / 64);
    pack_transpose_kernel<<<g1, 256, 0, stream>>>(in_bits, bitsT);

    dim3 g2(NN / NPB, BB / BPB);
    lookup_kernel<<<g2, 256, 0, stream>>>(conn, table, bitsT, out);
}

// Round 5
// 46.451 us; speedup vs baseline: 1.1357x; 1.0756x over previous
//
#include <hip/hip_runtime.h>
#include <stdint.h>

#define BB 1024    // batches
#define TT 1024    // input bits per batch
#define NN 2048    // neurons
#define NBITS 16   // address bits
#define MM 65536   // table entries per neuron
#define BW 16      // u64 words per t (= BB/64)

// ---------- K1: transpose+pack input_bits (B x T int32) -> bitsT[t][w] ----------
__global__ void pack_transpose_kernel(const int* __restrict__ in,
                                      unsigned long long* __restrict__ bitsT) {
    const int lane = threadIdx.x & 63;
    const int wave = threadIdx.x >> 6;
    const int w  = blockIdx.y;
    const int t0 = blockIdx.x * 64 + wave * 16;
    const int b  = w * 64 + lane;
    const int* row = in + (size_t)b * TT;
    #pragma unroll
    for (int i = 0; i < 16; ++i) {
        const int t = t0 + i;
        const int v = row[t];
        unsigned long long m = __ballot(v != 0);
        if (lane == 0) bitsT[(size_t)t * BW + w] = m;
    }
}

// ---------- K3: one block per neuron; bucket-sorted gather ----------
// Per block: build all 1024 addresses for row n, counting-sort into 64
// buckets (1K entries = 4KB of table each) in LDS, gather in sorted order
// (each wave instr spans ~16KB of the row -> DRAM page locality, dup-line
// merge), pack results to bits: resbitsT[w][n] bit (b&63), w = b>>6.
__global__ __launch_bounds__(256) void sorted_gather_kernel(
        const int* __restrict__ conn,
        const float* __restrict__ table,
        const unsigned long long* __restrict__ bitsT,
        unsigned long long* __restrict__ resbitsT) {
    __shared__ unsigned long long sb[NBITS * BW];   // 2 KB: bit words
    __shared__ unsigned int hist[64];
    __shared__ unsigned int cursor[64];
    __shared__ unsigned int sorted[BB];             // 4 KB: (addr<<16)|b
    __shared__ unsigned char resb[BB];              // 1 KB: result per b

    const int tid = threadIdx.x;
    const int n   = blockIdx.x;

    // stage the 16 needed bitsT rows (16 u64 each). thread <-> (k=tid>>4, w=tid&15)
    {
        const int k = tid >> 4;
        const int w = tid & 15;
        const int t = conn[n * NBITS + k];          // broadcast among 16 threads
        sb[k * BW + w] = bitsT[(size_t)t * BW + w]; // 128B coalesced per k-group
    }
    if (tid < 64) hist[tid] = 0;
    __syncthreads();

    // addresses for b = 4*tid + j, j=0..3 (all share word index tid>>4)
    const int wi = tid >> 4;
    unsigned long long wreg[NBITS];
    #pragma unroll
    for (int k = 0; k < NBITS; ++k) wreg[k] = sb[k * BW + wi];  // broadcast reads

    unsigned int addr[4];
    #pragma unroll
    for (int j = 0; j < 4; ++j) {
        const int bit = (4 * tid + j) & 63;
        unsigned int a = 0;
        #pragma unroll
        for (int k = 0; k < NBITS; ++k)
            a |= (unsigned int)((wreg[k] >> bit) & 1ull) << (NBITS - 1 - k);
        addr[j] = a;
        atomicAdd(&hist[a >> 10], 1u);
    }
    __syncthreads();

    // exclusive prefix sum over 64 buckets (wave 0)
    if (tid < 64) {
        const unsigned int v = hist[tid];
        unsigned int s = v;
        #pragma unroll
        for (int d = 1; d < 64; d <<= 1) {
            const unsigned int t2 = (unsigned int)__shfl_up((int)s, d, 64);
            if (tid >= d) s += t2;
        }
        cursor[tid] = s - v;                        // exclusive start
    }
    __syncthreads();

    // scatter into sorted order (bucket granularity)
    #pragma unroll
    for (int j = 0; j < 4; ++j) {
        const unsigned int a   = addr[j];
        const unsigned int pos = atomicAdd(&cursor[a >> 10], 1u);
        sorted[pos] = (a << 16) | (unsigned int)(4 * tid + j);
    }
    __syncthreads();

    // gather in sorted order: wave wv, iter j covers 64 consecutive sorted items
    const int lane = tid & 63;
    const int wv   = tid >> 6;
    const float* trow = table + (size_t)n * MM;
    unsigned int it[4];
    float v[4];
    #pragma unroll
    for (int j = 0; j < 4; ++j) it[j] = sorted[wv * 256 + j * 64 + lane];
    #pragma unroll
    for (int j = 0; j < 4; ++j) v[j] = trow[it[j] >> 16];   // 4 gathers in flight
    #pragma unroll
    for (int j = 0; j < 4; ++j)
        resb[it[j] & 0xFFFFu] = (v[j] == 1.0f) ? 1 : 0;
    __syncthreads();

    // pack: word w covers b in [w*64, w*64+64); bit lane = b = w*64+lane
    #pragma unroll
    for (int w4 = 0; w4 < 4; ++w4) {
        const int w = wv * 4 + w4;
        const unsigned long long m = __ballot(resb[w * 64 + lane] != 0);
        if (lane == 0) resbitsT[(size_t)w * NN + n] = m;
    }
}

// ---------- K4: expand resbitsT bits -> out[b][n] int32, fully coalesced ----------
__global__ void expand_kernel(const unsigned long long* __restrict__ resbitsT,
                              int* __restrict__ out) {
    const int idx = blockIdx.x * 256 + threadIdx.x;   // idx = b*NN + n
    const int n = idx & (NN - 1);
    const int b = idx >> 11;
    const unsigned long long w = resbitsT[(size_t)(b >> 6) * NN + n]; // L2-resident
    const int r = (int)((w >> (b & 63)) & 1ull);
    __builtin_nontemporal_store(r, &out[idx]);
}

// ---------- fallback (round-4 style direct lookup, needs only 128KB ws) ----------
__global__ __launch_bounds__(256) void lookup_direct_kernel(
        const int* __restrict__ conn,
        const float* __restrict__ table,
        const unsigned long long* __restrict__ bitsT,
        int* __restrict__ out) {
    const int tn = threadIdx.x & 15;
    const int s  = threadIdx.x >> 4;
    const int n  = blockIdx.x * 16 + tn;
    const int b0 = blockIdx.y * 256 + s * 16;
    int tk[NBITS];
    #pragma unroll
    for (int k = 0; k < NBITS; ++k) tk[k] = conn[n * NBITS + k];
    unsigned int hw[NBITS];
    const int w  = b0 >> 6;
    const int jb = b0 & 63;
    #pragma unroll
    for (int k = 0; k < NBITS; ++k) {
        unsigned long long word = bitsT[(size_t)tk[k] * BW + w];
        hw[k] = (unsigned int)(word >> jb) & 0xFFFFu;
    }
    const float* trow = table + (size_t)n * MM;
    #pragma unroll
    for (int j = 0; j < 16; ++j) {
        unsigned int a = 0;
        #pragma unroll
        for (int k = 0; k < NBITS; ++k)
            a |= ((hw[k] >> j) & 1u) << (NBITS - 1 - k);
        out[(size_t)(b0 + j) * NN + n] = (trow[a] == 1.0f) ? 1 : 0;
    }
}

extern "C" void kernel_launch(void* const* d_in, const int* in_sizes, int n_in,
                              void* d_out, int out_size, void* d_ws, size_t ws_size,
                              hipStream_t stream) {
    const int*   in_bits = (const int*)d_in[0];    // (B, T) int32
    const int*   conn    = (const int*)d_in[1];    // (N, NB) int32
    const float* table   = (const float*)d_in[2];  // (N, M) float32
    int* out = (int*)d_out;                        // (B, N) bool -> int32 0/1

    const size_t bitsT_bytes = (size_t)TT * BW * 8;          // 128 KB
    const size_t res_bytes   = (size_t)BW * NN * 8;          // 256 KB
    unsigned long long* bitsT    = (unsigned long long*)d_ws;
    unsigned long long* resbitsT = (unsigned long long*)((char*)d_ws + bitsT_bytes);

    dim3 g1(TT / 64, BB / 64);
    pack_transpose_kernel<<<g1, 256, 0, stream>>>(in_bits, bitsT);

    if (ws_size >= bitsT_bytes + res_bytes) {
        sorted_gather_kernel<<<NN, 256, 0, stream>>>(conn, table, bitsT, resbitsT);
        expand_kernel<<<(BB * NN) / 256, 256, 0, stream>>>(resbitsT, out);
    } else {
        dim3 g2(NN / 16, BB / 256);
        lookup_direct_kernel<<<g2, 256, 0, stream>>>(conn, table, bitsT, out);
    }
}